// Round 12
// baseline (68.547 us; speedup 1.0000x reference)
//
#include <hip/hip_runtime.h>

// RetinaNetFocalLoss on MI355X (gfx950).
// Inputs: clas_preds (16,49152,80) f32, bbox_preds (16,49152,4) f32,
//         bbox_tgts (16,64,4) f32 tlbr, clas_tgts (16,64) i32, anchors (49152,4) f32 cthw.
// Output: single f32 scalar.
//
// v12 = v11 with occupancy raised: __launch_bounds__(256, 8) -> 8 waves/EU
// (32 waves/CU, 8 blocks/CU) vs previous 4. VGPR=32, LDS ~3KB permit it.
// Everything else identical (quad-rcp focal, 4-deep pipeline, 1:1 parity
// roles, separate finalize).

#define A_CNT 49152
#define T_CNT 64
#define C_CNT 80
#define ABLK  256
#define NBLK  (A_CNT / ABLK)   // 192
#define B_CNT 16
#define NSLOT (B_CNT * NBLK)   // 3072

#define LN2   0.6931471806f
#define RLN2  1.44269504f

typedef float f32x4 __attribute__((ext_vector_type(4)));
typedef float f32x2 __attribute__((ext_vector_type(2)));

// --- quad-rcp focal: acc += sum_i sigma(x_i)^2 * log2(1+e^{x_i}) ---
// 4 exp + 1 rcp + 4 log per float4. Caller scales by 0.25*ln2.
__device__ __forceinline__ float focal4q(f32x4 v, float acc) {
    float e0 = __builtin_amdgcn_exp2f(v.x * RLN2);
    float e1 = __builtin_amdgcn_exp2f(v.y * RLN2);
    float e2 = __builtin_amdgcn_exp2f(v.z * RLN2);
    float e3 = __builtin_amdgcn_exp2f(v.w * RLN2);
    float t0 = 1.0f + e0, t1 = 1.0f + e1, t2 = 1.0f + e2, t3 = 1.0f + e3;
    float t01 = t0 * t1, t23 = t2 * t3;
    float r   = __builtin_amdgcn_rcpf(t01 * t23);   // 1/(t0 t1 t2 t3)
    float r01 = r * t23, r23 = r * t01;             // 1/(t0t1), 1/(t2t3)
    float s0 = e0 * (r01 * t1);                     // e0/t0
    float s1 = e1 * (r01 * t0);
    float s2 = e2 * (r23 * t3);
    float s3 = e3 * (r23 * t2);
    float L0 = __builtin_amdgcn_logf(t0);
    float L1 = __builtin_amdgcn_logf(t1);
    float L2 = __builtin_amdgcn_logf(t2);
    float L3 = __builtin_amdgcn_logf(t3);
    acc += ((s0 * s0) * L0 + (s1 * s1) * L1)
         + ((s2 * s2) * L2 + (s3 * s3) * L3);
    return acc;
}

// scalar-pair form (match-side corrections; rare)
__device__ __forceinline__ f32x2 focal2(f32x2 x, f32x2 acc) {
    f32x2 xs = x * RLN2;
    f32x2 e  = { __builtin_amdgcn_exp2f(xs.x), __builtin_amdgcn_exp2f(xs.y) };
    f32x2 t  = e + 1.0f;
    f32x2 iv = { __builtin_amdgcn_rcpf(t.x), __builtin_amdgcn_rcpf(t.y) };
    f32x2 ps = e * iv;
    f32x2 L  = { __builtin_amdgcn_logf(t.x), __builtin_amdgcn_logf(t.y) };
    return (ps * ps) * L + acc;
}
__device__ __forceinline__ float focal4s(f32x4 v) {
    f32x2 a = focal2((f32x2){v.x, v.y}, (f32x2){0.0f, 0.0f});
    a = focal2((f32x2){v.z, v.w}, a);
    return a.x + a.y;
}

__global__ __launch_bounds__(ABLK, 8) void rnfl_main(
    const float* __restrict__ clas_preds,
    const float* __restrict__ bbox_preds,
    const float* __restrict__ bbox_tgts,
    const int*   __restrict__ clas_tgts,
    const float* __restrict__ anchors,
    float* __restrict__ bb_part,
    float* __restrict__ fl_part,
    float* __restrict__ flc_part,
    float* __restrict__ m_part)
{
    const int tid  = threadIdx.x;
    const int g    = blockIdx.x;
    const int lane = tid & 63, wave = tid >> 6;

    __shared__ float4 tbox[T_CNT];
    __shared__ f32x2  tX1v[T_CNT / 2], tY1v[T_CNT / 2];
    __shared__ f32x2  tX2v[T_CNT / 2], tY2v[T_CNT / 2];
    __shared__ f32x2  tSv[T_CNT / 2];
    __shared__ int    tcl[T_CNT];
    __shared__ int    wcnt[4];
    __shared__ int    excl_idx[ABLK];
    __shared__ float  rv[4][4];

    const bool is_match = (g & 1);
    const int  bid2 = g >> 1;            // [0, 3072)
    const int  b    = bid2 / NBLK;
    const int  bx   = bid2 - b * NBLK;

    if (!is_match) {
        // ================= FOCAL STREAM =================
        const f32x4* cp4 = reinterpret_cast<const f32x4*>(clas_preds)
                         + ((size_t)b * A_CNT + bx * ABLK) * (C_CNT / 4);

        // 4-deep explicit pipeline; full unroll keeps buf indices static.
        f32x4 buf[4];
#pragma unroll
        for (int i = 0; i < 4; ++i)
            buf[i] = cp4[i * ABLK + tid];

        float acc = 0.0f;
#pragma unroll
        for (int k = 0; k < 20; ++k) {
            f32x4 cur = buf[k & 3];
            if (k + 4 < 20)
                buf[k & 3] = cp4[(k + 4) * ABLK + tid];
            acc = focal4q(cur, acc);
        }
        float fl = acc * (0.25f * LN2);

#pragma unroll
        for (int off = 32; off > 0; off >>= 1)
            fl += __shfl_down(fl, off);
        if (lane == 0) rv[wave][0] = fl;
        __syncthreads();
        if (tid == 0)
            fl_part[b * NBLK + bx] = rv[0][0] + rv[1][0] + rv[2][0] + rv[3][0];
        return;
    }

    // ================= MATCH =================
    const int a0 = bx * ABLK;

    if (tid < T_CNT) {
        float4 bt = reinterpret_cast<const float4*>(bbox_tgts)[b * T_CNT + tid];
        // tlbr -> cthw -> tlbr (reference roundtrip)
        float cx = (bt.x + bt.z) * 0.5f;
        float cy = (bt.y + bt.w) * 0.5f;
        float sx = bt.z - bt.x;
        float sy = bt.w - bt.y;
        float4 tb;
        tb.x = cx - sx * 0.5f;
        tb.y = cy - sy * 0.5f;
        tb.z = cx + sx * 0.5f;
        tb.w = cy + sy * 0.5f;
        tbox[tid] = tb;
        ((float*)tX1v)[tid] = tb.x;
        ((float*)tY1v)[tid] = tb.y;
        ((float*)tX2v)[tid] = tb.z;
        ((float*)tY2v)[tid] = tb.w;
        ((float*)tSv)[tid]  = (tb.z - tb.x) * (tb.w - tb.y) + 1e-8f;
        tcl[tid] = clas_tgts[b * T_CNT + tid];
    }
    __syncthreads();

    const int a = a0 + tid;
    float4 anc = reinterpret_cast<const float4*>(anchors)[a];
    const float ax1 = anc.x - anc.z * 0.5f;
    const float ay1 = anc.y - anc.w * 0.5f;
    const float ax2 = anc.x + anc.z * 0.5f;
    const float ay2 = anc.y + anc.w * 0.5f;
    const float areaA = anc.z * anc.w;
    const f32x2 A1 = {ax1, ax1}, B1 = {ay1, ay1};
    const f32x2 A2 = {ax2, ax2}, B2 = {ay2, ay2};
    const f32x2 SA = {areaA, areaA};
    const f32x2 Z  = {0.0f, 0.0f};

    float bn = -1.0f, bd = 1.0f;
    int   bj = 0;
#pragma unroll 4
    for (int p = 0; p < T_CNT / 2; ++p) {
        f32x2 ix1 = __builtin_elementwise_max(A1, tX1v[p]);
        f32x2 iy1 = __builtin_elementwise_max(B1, tY1v[p]);
        f32x2 ix2 = __builtin_elementwise_min(A2, tX2v[p]);
        f32x2 iy2 = __builtin_elementwise_min(B2, tY2v[p]);
        f32x2 w = __builtin_elementwise_max(ix2 - ix1, Z);
        f32x2 h = __builtin_elementwise_max(iy2 - iy1, Z);
        f32x2 inter = w * h;
        f32x2 den = (SA + tSv[p]) - inter;
        if (inter.x * bd > bn * den.x) { bn = inter.x; bd = den.x; bj = 2 * p; }
        if (inter.y * bd > bn * den.y) { bn = inter.y; bd = den.y; bj = 2 * p + 1; }
    }

    const f32x4* cp4b = reinterpret_cast<const f32x4*>(clas_preds)
                      + ((size_t)b * A_CNT + a0) * (C_CNT / 4);

    float bb = 0.0f, flc = 0.0f, craw = 0.0f, mloc = 0.0f;
    bool  excl = false;

    if (bn > 0.5f * bd) {                    // iou > MATCH_THR
        mloc = 1.0f;
        int code = tcl[bj] - 1;              // hot class in [0,79]
        float4 tb = tbox[bj];
        float gx = (tb.x + tb.z) * 0.5f;
        float gy = (tb.y + tb.w) * 0.5f;
        float gw = tb.z - tb.x;
        float gh = tb.w - tb.y;
        float4 bp = reinterpret_cast<const float4*>(bbox_preds)[(size_t)b * A_CNT + a];
        float t0 = ((gx - anc.x) / anc.z) * 10.0f;       // / SCALE 0.1
        float t1 = ((gy - anc.y) / anc.w) * 10.0f;
        float t2 = __logf(gw / anc.z + 1e-8f) * 5.0f;    // / SCALE 0.2
        float t3 = __logf(gh / anc.w + 1e-8f) * 5.0f;
        float d, ad;
        d = bp.x - t0; ad = fabsf(d); bb += (ad < 1.0f) ? 0.5f * d * d : ad - 0.5f;
        d = bp.y - t1; ad = fabsf(d); bb += (ad < 1.0f) ? 0.5f * d * d : ad - 0.5f;
        d = bp.z - t2; ad = fabsf(d); bb += (ad < 1.0f) ? 0.5f * d * d : ad - 0.5f;
        d = bp.w - t3; ad = fabsf(d); bb += (ad < 1.0f) ? 0.5f * d * d : ad - 0.5f;

        // hot focal correction (same exp/log primitives as streamer)
        float x  = clas_preds[((size_t)b * A_CNT + a) * C_CNT + code];
        float e  = __builtin_amdgcn_exp2f(x * RLN2);
        float t  = 1.0f + e;
        float inv = __builtin_amdgcn_rcpf(t);
        float ps = e * inv;
        float q  = 1.0f - ps;
        float L  = __builtin_amdgcn_logf(t);
        float sp = LN2 * L;
        flc = 0.75f * q * q * (sp - x) - 0.25f * ps * ps * sp;
    } else {
        excl = (bn >= 0.4f * bd);            // 0.4 <= iou <= 0.5: excluded
    }

    // compact excluded anchors (deterministic ballot order)
    unsigned long long bm = __ballot(excl);
    if (lane == 0) wcnt[wave] = __popcll(bm);
    __syncthreads();
    int wbase = 0;
#pragma unroll
    for (int w = 0; w < 4; ++w) wbase += (w < wave) ? wcnt[w] : 0;
    const int E = wcnt[0] + wcnt[1] + wcnt[2] + wcnt[3];
    if (excl) {
        int rank = wbase + __popcll(bm & ((1ull << lane) - 1ull));
        excl_idx[rank] = tid;
    }
    __syncthreads();

    // subtract excluded anchors' unmasked focal (20 threads/anchor)
    for (int base = 0; base < E; base += 12) {
        int idx  = base + tid / 20;
        int part = tid % 20;
        if (tid < 240 && idx < E) {
            int al = excl_idx[idx];
            f32x4 v = cp4b[(size_t)al * 20 + part];
            craw -= focal4s(v);
        }
    }
    flc = fmaf(0.25f * LN2, craw, flc);

    // block reduction of {bb, flc, m}
#pragma unroll
    for (int off = 32; off > 0; off >>= 1) {
        bb   += __shfl_down(bb, off);
        flc  += __shfl_down(flc, off);
        mloc += __shfl_down(mloc, off);
    }
    if (lane == 0) { rv[wave][0] = bb; rv[wave][1] = flc; rv[wave][2] = mloc; }
    __syncthreads();
    if (tid == 0) {
        int slot = b * NBLK + bx;
        bb_part[slot]  = rv[0][0] + rv[1][0] + rv[2][0] + rv[3][0];
        flc_part[slot] = rv[0][1] + rv[1][1] + rv[2][1] + rv[3][1];
        m_part[slot]   = rv[0][2] + rv[1][2] + rv[2][2] + rv[3][2];
    }
}

// ---------- Finalize (separate dispatch; coalesced -> LDS -> reduce) ----------
__global__ __launch_bounds__(256) void rnfl_final(
    const float* __restrict__ bb_part,
    const float* __restrict__ fl_part,
    const float* __restrict__ flc_part,
    const float* __restrict__ m_part,
    float* __restrict__ out)
{
    __shared__ float bbL[NSLOT], flL[NSLOT], fcL[NSLOT], mL[NSLOT];  // 48 KB
    __shared__ float wacc[4];
    const int tid = threadIdx.x, lane = tid & 63, wave = tid >> 6;

#pragma unroll
    for (int k = 0; k < NSLOT / 256; ++k) {
        int s = k * 256 + tid;
        bbL[s] = bb_part[s];
        flL[s] = fl_part[s];
        fcL[s] = flc_part[s];
        mL[s]  = m_part[s];
    }
    __syncthreads();

    float lacc = 0.0f;
    for (int img = wave; img < B_CNT; img += 4) {
        float bb = 0.0f, fl = 0.0f, m = 0.0f;
#pragma unroll
        for (int s = 0; s < 3; ++s) {
            int i = img * NBLK + s * 64 + lane;
            bb += bbL[i];
            fl += flL[i] + fcL[i];
            m  += mL[i];
        }
#pragma unroll
        for (int off = 32; off > 0; off >>= 1) {
            bb += __shfl_down(bb, off);
            fl += __shfl_down(fl, off);
            m  += __shfl_down(m, off);
        }
        if (lane == 0)
            lacc += bb / fmaxf(m * 4.0f, 1.0f) + fl / fmaxf(m, 1.0f);
    }
    if (lane == 0) wacc[wave] = lacc;
    __syncthreads();
    if (tid == 0)
        out[0] = (wacc[0] + wacc[1] + wacc[2] + wacc[3]) / (float)B_CNT;
}

extern "C" void kernel_launch(void* const* d_in, const int* in_sizes, int n_in,
                              void* d_out, int out_size, void* d_ws, size_t ws_size,
                              hipStream_t stream)
{
    const float* clas_preds = (const float*)d_in[0];
    const float* bbox_preds = (const float*)d_in[1];
    const float* bbox_tgts  = (const float*)d_in[2];
    const int*   clas_tgts  = (const int*)d_in[3];
    const float* anchors    = (const float*)d_in[4];
    float* out = (float*)d_out;

    float* bb_part  = (float*)d_ws;
    float* fl_part  = bb_part  + NSLOT;
    float* flc_part = fl_part  + NSLOT;
    float* m_part   = flc_part + NSLOT;

    rnfl_main<<<2 * NSLOT, ABLK, 0, stream>>>(clas_preds, bbox_preds, bbox_tgts,
                                              clas_tgts, anchors,
                                              bb_part, fl_part, flc_part, m_part);
    rnfl_final<<<1, 256, 0, stream>>>(bb_part, fl_part, flc_part, m_part, out);
}

// Round 13
// 68.324 us; speedup vs baseline: 1.0033x; 1.0033x over previous
//
#include <hip/hip_runtime.h>

// RetinaNetFocalLoss on MI355X (gfx950).
// Inputs: clas_preds (16,49152,80) f32, bbox_preds (16,49152,4) f32,
//         bbox_tgts (16,64,4) f32 tlbr, clas_tgts (16,64) i32, anchors (49152,4) f32 cthw.
// Output: single f32 scalar.
//
// v13 = v12 with the focal prefetch pipeline deepened 4 -> 8 (buf[8], fully
// static indices; prologue/steady/tail split). Doubles in-flight bytes per CU
// (128 KB -> 256 KB) at unchanged occupancy (VGPR stays <= 64, enforced by
// __launch_bounds__(256,8)). Tests the exposed-HBM-latency theory.

#define A_CNT 49152
#define T_CNT 64
#define C_CNT 80
#define ABLK  256
#define NBLK  (A_CNT / ABLK)   // 192
#define B_CNT 16
#define NSLOT (B_CNT * NBLK)   // 3072

#define LN2   0.6931471806f
#define RLN2  1.44269504f

typedef float f32x4 __attribute__((ext_vector_type(4)));
typedef float f32x2 __attribute__((ext_vector_type(2)));

// --- quad-rcp focal: acc += sum_i sigma(x_i)^2 * log2(1+e^{x_i}) ---
// 4 exp + 1 rcp + 4 log per float4. Caller scales by 0.25*ln2.
__device__ __forceinline__ float focal4q(f32x4 v, float acc) {
    float e0 = __builtin_amdgcn_exp2f(v.x * RLN2);
    float e1 = __builtin_amdgcn_exp2f(v.y * RLN2);
    float e2 = __builtin_amdgcn_exp2f(v.z * RLN2);
    float e3 = __builtin_amdgcn_exp2f(v.w * RLN2);
    float t0 = 1.0f + e0, t1 = 1.0f + e1, t2 = 1.0f + e2, t3 = 1.0f + e3;
    float t01 = t0 * t1, t23 = t2 * t3;
    float r   = __builtin_amdgcn_rcpf(t01 * t23);   // 1/(t0 t1 t2 t3)
    float r01 = r * t23, r23 = r * t01;             // 1/(t0t1), 1/(t2t3)
    float s0 = e0 * (r01 * t1);                     // e0/t0
    float s1 = e1 * (r01 * t0);
    float s2 = e2 * (r23 * t3);
    float s3 = e3 * (r23 * t2);
    float L0 = __builtin_amdgcn_logf(t0);
    float L1 = __builtin_amdgcn_logf(t1);
    float L2 = __builtin_amdgcn_logf(t2);
    float L3 = __builtin_amdgcn_logf(t3);
    acc += ((s0 * s0) * L0 + (s1 * s1) * L1)
         + ((s2 * s2) * L2 + (s3 * s3) * L3);
    return acc;
}

// scalar-pair form (match-side corrections; rare)
__device__ __forceinline__ f32x2 focal2(f32x2 x, f32x2 acc) {
    f32x2 xs = x * RLN2;
    f32x2 e  = { __builtin_amdgcn_exp2f(xs.x), __builtin_amdgcn_exp2f(xs.y) };
    f32x2 t  = e + 1.0f;
    f32x2 iv = { __builtin_amdgcn_rcpf(t.x), __builtin_amdgcn_rcpf(t.y) };
    f32x2 ps = e * iv;
    f32x2 L  = { __builtin_amdgcn_logf(t.x), __builtin_amdgcn_logf(t.y) };
    return (ps * ps) * L + acc;
}
__device__ __forceinline__ float focal4s(f32x4 v) {
    f32x2 a = focal2((f32x2){v.x, v.y}, (f32x2){0.0f, 0.0f});
    a = focal2((f32x2){v.z, v.w}, a);
    return a.x + a.y;
}

__global__ __launch_bounds__(ABLK, 8) void rnfl_main(
    const float* __restrict__ clas_preds,
    const float* __restrict__ bbox_preds,
    const float* __restrict__ bbox_tgts,
    const int*   __restrict__ clas_tgts,
    const float* __restrict__ anchors,
    float* __restrict__ bb_part,
    float* __restrict__ fl_part,
    float* __restrict__ flc_part,
    float* __restrict__ m_part)
{
    const int tid  = threadIdx.x;
    const int g    = blockIdx.x;
    const int lane = tid & 63, wave = tid >> 6;

    __shared__ float4 tbox[T_CNT];
    __shared__ f32x2  tX1v[T_CNT / 2], tY1v[T_CNT / 2];
    __shared__ f32x2  tX2v[T_CNT / 2], tY2v[T_CNT / 2];
    __shared__ f32x2  tSv[T_CNT / 2];
    __shared__ int    tcl[T_CNT];
    __shared__ int    wcnt[4];
    __shared__ int    excl_idx[ABLK];
    __shared__ float  rv[4][4];

    const bool is_match = (g & 1);
    const int  bid2 = g >> 1;            // [0, 3072)
    const int  b    = bid2 / NBLK;
    const int  bx   = bid2 - b * NBLK;

    if (!is_match) {
        // ================= FOCAL STREAM =================
        const f32x4* cp4 = reinterpret_cast<const f32x4*>(clas_preds)
                         + ((size_t)b * A_CNT + bx * ABLK) * (C_CNT / 4);

        // 8-deep prefetch pipeline, fully static buffer indices.
        f32x4 buf[8];
#pragma unroll
        for (int i = 0; i < 8; ++i)
            buf[i] = cp4[i * ABLK + tid];

        float acc = 0.0f;
        // steady state: consume k, reload slot with k+8  (k = 0..11)
#pragma unroll
        for (int k = 0; k < 12; ++k) {
            f32x4 cur = buf[k & 7];
            buf[k & 7] = cp4[(k + 8) * ABLK + tid];
            acc = focal4q(cur, acc);
        }
        // tail: consume remaining 8 (k = 12..19)
#pragma unroll
        for (int k = 12; k < 20; ++k)
            acc = focal4q(buf[k & 7], acc);

        float fl = acc * (0.25f * LN2);

#pragma unroll
        for (int off = 32; off > 0; off >>= 1)
            fl += __shfl_down(fl, off);
        if (lane == 0) rv[wave][0] = fl;
        __syncthreads();
        if (tid == 0)
            fl_part[b * NBLK + bx] = rv[0][0] + rv[1][0] + rv[2][0] + rv[3][0];
        return;
    }

    // ================= MATCH =================
    const int a0 = bx * ABLK;

    if (tid < T_CNT) {
        float4 bt = reinterpret_cast<const float4*>(bbox_tgts)[b * T_CNT + tid];
        // tlbr -> cthw -> tlbr (reference roundtrip)
        float cx = (bt.x + bt.z) * 0.5f;
        float cy = (bt.y + bt.w) * 0.5f;
        float sx = bt.z - bt.x;
        float sy = bt.w - bt.y;
        float4 tb;
        tb.x = cx - sx * 0.5f;
        tb.y = cy - sy * 0.5f;
        tb.z = cx + sx * 0.5f;
        tb.w = cy + sy * 0.5f;
        tbox[tid] = tb;
        ((float*)tX1v)[tid] = tb.x;
        ((float*)tY1v)[tid] = tb.y;
        ((float*)tX2v)[tid] = tb.z;
        ((float*)tY2v)[tid] = tb.w;
        ((float*)tSv)[tid]  = (tb.z - tb.x) * (tb.w - tb.y) + 1e-8f;
        tcl[tid] = clas_tgts[b * T_CNT + tid];
    }
    __syncthreads();

    const int a = a0 + tid;
    float4 anc = reinterpret_cast<const float4*>(anchors)[a];
    const float ax1 = anc.x - anc.z * 0.5f;
    const float ay1 = anc.y - anc.w * 0.5f;
    const float ax2 = anc.x + anc.z * 0.5f;
    const float ay2 = anc.y + anc.w * 0.5f;
    const float areaA = anc.z * anc.w;
    const f32x2 A1 = {ax1, ax1}, B1 = {ay1, ay1};
    const f32x2 A2 = {ax2, ax2}, B2 = {ay2, ay2};
    const f32x2 SA = {areaA, areaA};
    const f32x2 Z  = {0.0f, 0.0f};

    float bn = -1.0f, bd = 1.0f;
    int   bj = 0;
#pragma unroll 4
    for (int p = 0; p < T_CNT / 2; ++p) {
        f32x2 ix1 = __builtin_elementwise_max(A1, tX1v[p]);
        f32x2 iy1 = __builtin_elementwise_max(B1, tY1v[p]);
        f32x2 ix2 = __builtin_elementwise_min(A2, tX2v[p]);
        f32x2 iy2 = __builtin_elementwise_min(B2, tY2v[p]);
        f32x2 w = __builtin_elementwise_max(ix2 - ix1, Z);
        f32x2 h = __builtin_elementwise_max(iy2 - iy1, Z);
        f32x2 inter = w * h;
        f32x2 den = (SA + tSv[p]) - inter;
        if (inter.x * bd > bn * den.x) { bn = inter.x; bd = den.x; bj = 2 * p; }
        if (inter.y * bd > bn * den.y) { bn = inter.y; bd = den.y; bj = 2 * p + 1; }
    }

    const f32x4* cp4b = reinterpret_cast<const f32x4*>(clas_preds)
                      + ((size_t)b * A_CNT + a0) * (C_CNT / 4);

    float bb = 0.0f, flc = 0.0f, craw = 0.0f, mloc = 0.0f;
    bool  excl = false;

    if (bn > 0.5f * bd) {                    // iou > MATCH_THR
        mloc = 1.0f;
        int code = tcl[bj] - 1;              // hot class in [0,79]
        float4 tb = tbox[bj];
        float gx = (tb.x + tb.z) * 0.5f;
        float gy = (tb.y + tb.w) * 0.5f;
        float gw = tb.z - tb.x;
        float gh = tb.w - tb.y;
        float4 bp = reinterpret_cast<const float4*>(bbox_preds)[(size_t)b * A_CNT + a];
        float t0 = ((gx - anc.x) / anc.z) * 10.0f;       // / SCALE 0.1
        float t1 = ((gy - anc.y) / anc.w) * 10.0f;
        float t2 = __logf(gw / anc.z + 1e-8f) * 5.0f;    // / SCALE 0.2
        float t3 = __logf(gh / anc.w + 1e-8f) * 5.0f;
        float d, ad;
        d = bp.x - t0; ad = fabsf(d); bb += (ad < 1.0f) ? 0.5f * d * d : ad - 0.5f;
        d = bp.y - t1; ad = fabsf(d); bb += (ad < 1.0f) ? 0.5f * d * d : ad - 0.5f;
        d = bp.z - t2; ad = fabsf(d); bb += (ad < 1.0f) ? 0.5f * d * d : ad - 0.5f;
        d = bp.w - t3; ad = fabsf(d); bb += (ad < 1.0f) ? 0.5f * d * d : ad - 0.5f;

        // hot focal correction (same exp/log primitives as streamer)
        float x  = clas_preds[((size_t)b * A_CNT + a) * C_CNT + code];
        float e  = __builtin_amdgcn_exp2f(x * RLN2);
        float t  = 1.0f + e;
        float inv = __builtin_amdgcn_rcpf(t);
        float ps = e * inv;
        float q  = 1.0f - ps;
        float L  = __builtin_amdgcn_logf(t);
        float sp = LN2 * L;
        flc = 0.75f * q * q * (sp - x) - 0.25f * ps * ps * sp;
    } else {
        excl = (bn >= 0.4f * bd);            // 0.4 <= iou <= 0.5: excluded
    }

    // compact excluded anchors (deterministic ballot order)
    unsigned long long bm = __ballot(excl);
    if (lane == 0) wcnt[wave] = __popcll(bm);
    __syncthreads();
    int wbase = 0;
#pragma unroll
    for (int w = 0; w < 4; ++w) wbase += (w < wave) ? wcnt[w] : 0;
    const int E = wcnt[0] + wcnt[1] + wcnt[2] + wcnt[3];
    if (excl) {
        int rank = wbase + __popcll(bm & ((1ull << lane) - 1ull));
        excl_idx[rank] = tid;
    }
    __syncthreads();

    // subtract excluded anchors' unmasked focal (20 threads/anchor)
    for (int base = 0; base < E; base += 12) {
        int idx  = base + tid / 20;
        int part = tid % 20;
        if (tid < 240 && idx < E) {
            int al = excl_idx[idx];
            f32x4 v = cp4b[(size_t)al * 20 + part];
            craw -= focal4s(v);
        }
    }
    flc = fmaf(0.25f * LN2, craw, flc);

    // block reduction of {bb, flc, m}
#pragma unroll
    for (int off = 32; off > 0; off >>= 1) {
        bb   += __shfl_down(bb, off);
        flc  += __shfl_down(flc, off);
        mloc += __shfl_down(mloc, off);
    }
    if (lane == 0) { rv[wave][0] = bb; rv[wave][1] = flc; rv[wave][2] = mloc; }
    __syncthreads();
    if (tid == 0) {
        int slot = b * NBLK + bx;
        bb_part[slot]  = rv[0][0] + rv[1][0] + rv[2][0] + rv[3][0];
        flc_part[slot] = rv[0][1] + rv[1][1] + rv[2][1] + rv[3][1];
        m_part[slot]   = rv[0][2] + rv[1][2] + rv[2][2] + rv[3][2];
    }
}

// ---------- Finalize (separate dispatch; coalesced -> LDS -> reduce) ----------
__global__ __launch_bounds__(256) void rnfl_final(
    const float* __restrict__ bb_part,
    const float* __restrict__ fl_part,
    const float* __restrict__ flc_part,
    const float* __restrict__ m_part,
    float* __restrict__ out)
{
    __shared__ float bbL[NSLOT], flL[NSLOT], fcL[NSLOT], mL[NSLOT];  // 48 KB
    __shared__ float wacc[4];
    const int tid = threadIdx.x, lane = tid & 63, wave = tid >> 6;

#pragma unroll
    for (int k = 0; k < NSLOT / 256; ++k) {
        int s = k * 256 + tid;
        bbL[s] = bb_part[s];
        flL[s] = fl_part[s];
        fcL[s] = flc_part[s];
        mL[s]  = m_part[s];
    }
    __syncthreads();

    float lacc = 0.0f;
    for (int img = wave; img < B_CNT; img += 4) {
        float bb = 0.0f, fl = 0.0f, m = 0.0f;
#pragma unroll
        for (int s = 0; s < 3; ++s) {
            int i = img * NBLK + s * 64 + lane;
            bb += bbL[i];
            fl += flL[i] + fcL[i];
            m  += mL[i];
        }
#pragma unroll
        for (int off = 32; off > 0; off >>= 1) {
            bb += __shfl_down(bb, off);
            fl += __shfl_down(fl, off);
            m  += __shfl_down(m, off);
        }
        if (lane == 0)
            lacc += bb / fmaxf(m * 4.0f, 1.0f) + fl / fmaxf(m, 1.0f);
    }
    if (lane == 0) wacc[wave] = lacc;
    __syncthreads();
    if (tid == 0)
        out[0] = (wacc[0] + wacc[1] + wacc[2] + wacc[3]) / (float)B_CNT;
}

extern "C" void kernel_launch(void* const* d_in, const int* in_sizes, int n_in,
                              void* d_out, int out_size, void* d_ws, size_t ws_size,
                              hipStream_t stream)
{
    const float* clas_preds = (const float*)d_in[0];
    const float* bbox_preds = (const float*)d_in[1];
    const float* bbox_tgts  = (const float*)d_in[2];
    const int*   clas_tgts  = (const int*)d_in[3];
    const float* anchors    = (const float*)d_in[4];
    float* out = (float*)d_out;

    float* bb_part  = (float*)d_ws;
    float* fl_part  = bb_part  + NSLOT;
    float* flc_part = fl_part  + NSLOT;
    float* m_part   = flc_part + NSLOT;

    rnfl_main<<<2 * NSLOT, ABLK, 0, stream>>>(clas_preds, bbox_preds, bbox_tgts,
                                              clas_tgts, anchors,
                                              bb_part, fl_part, flc_part, m_part);
    rnfl_final<<<1, 256, 0, stream>>>(bb_part, fl_part, flc_part, m_part, out);
}

// Round 14
// 57.187 us; speedup vs baseline: 1.1986x; 1.1947x over previous
//
#include <hip/hip_runtime.h>

// RetinaNetFocalLoss on MI355X (gfx950).
// Inputs: clas_preds (16,49152,80) f32, bbox_preds (16,49152,4) f32,
//         bbox_tgts (16,64,4) f32 tlbr, clas_tgts (16,64) i32, anchors (49152,4) f32 cthw.
// Output: single f32 scalar.
//
// v14: FUSED single-role blocks (3072): each block issues its 8-deep focal
// prefetch FIRST (memory busy from cycle 0), runs match while loads fly,
// then streams focal with a per-anchor mask (codes in LDS, hoisted to a
// 20-bit register mask). Eliminates: separate match blocks, the excluded-
// anchor subtraction pass, duplicated sparse slab reads. Separate finalize.

#define A_CNT 49152
#define T_CNT 64
#define C_CNT 80
#define ABLK  256
#define NBLK  (A_CNT / ABLK)   // 192
#define B_CNT 16
#define NSLOT (B_CNT * NBLK)   // 3072

#define LN2   0.6931471806f
#define RLN2  1.44269504f

typedef float f32x4 __attribute__((ext_vector_type(4)));

// sum_i sigma(x_i)^2 * log2(1+e^{x_i}) over a float4 (quad-rcp: 4 exp + 1 rcp
// + 4 log). Caller applies mask and the final 0.25*ln2 scale.
__device__ __forceinline__ float focal4q(f32x4 v) {
    float e0 = __builtin_amdgcn_exp2f(v.x * RLN2);
    float e1 = __builtin_amdgcn_exp2f(v.y * RLN2);
    float e2 = __builtin_amdgcn_exp2f(v.z * RLN2);
    float e3 = __builtin_amdgcn_exp2f(v.w * RLN2);
    float t0 = 1.0f + e0, t1 = 1.0f + e1, t2 = 1.0f + e2, t3 = 1.0f + e3;
    float t01 = t0 * t1, t23 = t2 * t3;
    float r   = __builtin_amdgcn_rcpf(t01 * t23);   // 1/(t0 t1 t2 t3)
    float r01 = r * t23, r23 = r * t01;
    float s0 = e0 * (r01 * t1);                     // e_i/t_i
    float s1 = e1 * (r01 * t0);
    float s2 = e2 * (r23 * t3);
    float s3 = e3 * (r23 * t2);
    float L0 = __builtin_amdgcn_logf(t0);
    float L1 = __builtin_amdgcn_logf(t1);
    float L2 = __builtin_amdgcn_logf(t2);
    float L3 = __builtin_amdgcn_logf(t3);
    return ((s0 * s0) * L0 + (s1 * s1) * L1)
         + ((s2 * s2) * L2 + (s3 * s3) * L3);
}

__global__ __launch_bounds__(ABLK) void rnfl_main(
    const float* __restrict__ clas_preds,
    const float* __restrict__ bbox_preds,
    const float* __restrict__ bbox_tgts,
    const int*   __restrict__ clas_tgts,
    const float* __restrict__ anchors,
    float* __restrict__ bb_part,
    float* __restrict__ fl_part,
    float* __restrict__ m_part)
{
    const int tid  = threadIdx.x;
    const int g    = blockIdx.x;                // [0, 3072)
    const int lane = tid & 63, wave = tid >> 6;
    const int b    = g / NBLK;
    const int bx   = g - b * NBLK;
    const int a0   = bx * ABLK;

    __shared__ float4 tbox[T_CNT];
    __shared__ float  taT[T_CNT];
    __shared__ int    tcl[T_CNT];
    __shared__ int    codes[ABLK];
    __shared__ float  rv[4][4];

    const f32x4* cp4 = reinterpret_cast<const f32x4*>(clas_preds)
                     + ((size_t)b * A_CNT + a0) * (C_CNT / 4);

    // ---- 1. issue the focal prefetches FIRST (8 in flight during match) ----
    f32x4 buf[8];
#pragma unroll
    for (int i = 0; i < 8; ++i)
        buf[i] = cp4[i * ABLK + tid];

    // ---- 2. stage targets into LDS ----
    if (tid < T_CNT) {
        float4 bt = reinterpret_cast<const float4*>(bbox_tgts)[b * T_CNT + tid];
        // tlbr -> cthw -> tlbr (reference roundtrip)
        float cx = (bt.x + bt.z) * 0.5f;
        float cy = (bt.y + bt.w) * 0.5f;
        float sx = bt.z - bt.x;
        float sy = bt.w - bt.y;
        float4 tb;
        tb.x = cx - sx * 0.5f;
        tb.y = cy - sy * 0.5f;
        tb.z = cx + sx * 0.5f;
        tb.w = cy + sy * 0.5f;
        tbox[tid] = tb;
        taT[tid]  = sx * sy + 1e-8f;
        tcl[tid]  = clas_tgts[b * T_CNT + tid];
    }
    __syncthreads();

    // ---- 3. match (VALU; prefetches land underneath) ----
    const int a = a0 + tid;
    float4 anc = reinterpret_cast<const float4*>(anchors)[a];
    const float ax1 = anc.x - anc.z * 0.5f;
    const float ay1 = anc.y - anc.w * 0.5f;
    const float ax2 = anc.x + anc.z * 0.5f;
    const float ay2 = anc.y + anc.w * 0.5f;
    const float areaA = anc.z * anc.w;

    float bn = -1.0f, bd = 1.0f;
    int   bj = 0;
#pragma unroll 8
    for (int j = 0; j < T_CNT; ++j) {
        float4 tb = tbox[j];                 // wave-uniform b128 broadcast
        float ix1 = fmaxf(ax1, tb.x);
        float iy1 = fmaxf(ay1, tb.y);
        float ix2 = fminf(ax2, tb.z);
        float iy2 = fminf(ay2, tb.w);
        float w = fmaxf(ix2 - ix1, 0.0f);
        float h = fmaxf(iy2 - iy1, 0.0f);
        float inter = w * h;
        float den = (areaA + taT[j]) - inter;
        if (inter * bd > bn * den) { bn = inter; bd = den; bj = j; }  // first-max
    }

    int   code;
    float bb   = 0.0f;
    float flc  = 0.0f;
    float mloc = 0.0f;

    if (bn > 0.5f * bd) {                    // iou > MATCH_THR
        mloc = 1.0f;
        code = tcl[bj] - 1;                  // hot class in [0,79]
        float4 tb = tbox[bj];
        float gx = (tb.x + tb.z) * 0.5f;
        float gy = (tb.y + tb.w) * 0.5f;
        float gw = tb.z - tb.x;
        float gh = tb.w - tb.y;
        float4 bp = reinterpret_cast<const float4*>(bbox_preds)[(size_t)b * A_CNT + a];
        float t0 = ((gx - anc.x) / anc.z) * 10.0f;       // / SCALE 0.1
        float t1 = ((gy - anc.y) / anc.w) * 10.0f;
        float t2 = __logf(gw / anc.z + 1e-8f) * 5.0f;    // / SCALE 0.2
        float t3 = __logf(gh / anc.w + 1e-8f) * 5.0f;
        float d, ad;
        d = bp.x - t0; ad = fabsf(d); bb += (ad < 1.0f) ? 0.5f * d * d : ad - 0.5f;
        d = bp.y - t1; ad = fabsf(d); bb += (ad < 1.0f) ? 0.5f * d * d : ad - 0.5f;
        d = bp.z - t2; ad = fabsf(d); bb += (ad < 1.0f) ? 0.5f * d * d : ad - 0.5f;
        d = bp.w - t3; ad = fabsf(d); bb += (ad < 1.0f) ? 0.5f * d * d : ad - 0.5f;

        // hot focal correction: stream adds 0.25*ps^2*sp for the hot element;
        // replace with 0.75*(1-ps)^2*softplus(-x). (Read is L2-warm: this
        // element is inside the slab our prefetches are streaming.)
        float x  = clas_preds[((size_t)b * A_CNT + a) * C_CNT + code];
        float e  = __builtin_amdgcn_exp2f(x * RLN2);
        float t  = 1.0f + e;
        float inv = __builtin_amdgcn_rcpf(t);
        float ps = e * inv;
        float q  = 1.0f - ps;
        float L  = __builtin_amdgcn_logf(t);
        float sp = LN2 * L;                              // softplus(x)
        flc = 0.75f * q * q * (sp - x) - 0.25f * ps * ps * sp;
    } else {
        code = (bn >= 0.4f * bd) ? -2 : -1;  // -2 excluded, -1 background
    }
    codes[tid] = code;
    __syncthreads();

    // ---- 4. hoist per-anchor mask into a 20-bit register mask ----
    unsigned mbits = 0;
#pragma unroll
    for (int k = 0; k < 20; ++k) {
        int al = (unsigned)(k * ABLK + tid) / 20u;
        mbits |= (codes[al] >= -1 ? 1u : 0u) << k;
    }

    // ---- 5. masked focal stream (8-deep reload) ----
    float acc = 0.0f;
#pragma unroll
    for (int k = 0; k < 12; ++k) {
        f32x4 cur = buf[k & 7];
        buf[k & 7] = cp4[(k + 8) * ABLK + tid];
        float m = (float)((mbits >> k) & 1u);
        acc = fmaf(m, focal4q(cur), acc);
    }
#pragma unroll
    for (int k = 12; k < 20; ++k) {
        float m = (float)((mbits >> k) & 1u);
        acc = fmaf(m, focal4q(buf[k & 7]), acc);
    }
    float fl = fmaf(acc, 0.25f * LN2, flc);   // stream + hot correction

    // ---- 6. block reduction of {bb, fl, m} ----
#pragma unroll
    for (int off = 32; off > 0; off >>= 1) {
        bb   += __shfl_down(bb, off);
        fl   += __shfl_down(fl, off);
        mloc += __shfl_down(mloc, off);
    }
    if (lane == 0) { rv[wave][0] = bb; rv[wave][1] = fl; rv[wave][2] = mloc; }
    __syncthreads();
    if (tid == 0) {
        int slot = b * NBLK + bx;
        bb_part[slot] = rv[0][0] + rv[1][0] + rv[2][0] + rv[3][0];
        fl_part[slot] = rv[0][1] + rv[1][1] + rv[2][1] + rv[3][1];
        m_part[slot]  = rv[0][2] + rv[1][2] + rv[2][2] + rv[3][2];
    }
}

// ---------- Finalize (separate dispatch; coalesced -> LDS -> reduce) ----------
__global__ __launch_bounds__(256) void rnfl_final(
    const float* __restrict__ bb_part,
    const float* __restrict__ fl_part,
    const float* __restrict__ m_part,
    float* __restrict__ out)
{
    __shared__ float bbL[NSLOT], flL[NSLOT], mL[NSLOT];  // 36 KB
    __shared__ float wacc[4];
    const int tid = threadIdx.x, lane = tid & 63, wave = tid >> 6;

#pragma unroll
    for (int k = 0; k < NSLOT / 256; ++k) {   // 12 coalesced loads per array
        int s = k * 256 + tid;
        bbL[s] = bb_part[s];
        flL[s] = fl_part[s];
        mL[s]  = m_part[s];
    }
    __syncthreads();

    float lacc = 0.0f;
    for (int img = wave; img < B_CNT; img += 4) {
        float bb = 0.0f, fl = 0.0f, m = 0.0f;
#pragma unroll
        for (int s = 0; s < 3; ++s) {         // 3*64 = 192 = NBLK
            int i = img * NBLK + s * 64 + lane;
            bb += bbL[i];
            fl += flL[i];
            m  += mL[i];
        }
#pragma unroll
        for (int off = 32; off > 0; off >>= 1) {
            bb += __shfl_down(bb, off);
            fl += __shfl_down(fl, off);
            m  += __shfl_down(m, off);
        }
        if (lane == 0)
            lacc += bb / fmaxf(m * 4.0f, 1.0f) + fl / fmaxf(m, 1.0f);
    }
    if (lane == 0) wacc[wave] = lacc;
    __syncthreads();
    if (tid == 0)
        out[0] = (wacc[0] + wacc[1] + wacc[2] + wacc[3]) / (float)B_CNT;
}

extern "C" void kernel_launch(void* const* d_in, const int* in_sizes, int n_in,
                              void* d_out, int out_size, void* d_ws, size_t ws_size,
                              hipStream_t stream)
{
    const float* clas_preds = (const float*)d_in[0];
    const float* bbox_preds = (const float*)d_in[1];
    const float* bbox_tgts  = (const float*)d_in[2];
    const int*   clas_tgts  = (const int*)d_in[3];
    const float* anchors    = (const float*)d_in[4];
    float* out = (float*)d_out;

    float* bb_part = (float*)d_ws;
    float* fl_part = bb_part + NSLOT;
    float* m_part  = fl_part + NSLOT;

    rnfl_main<<<NSLOT, ABLK, 0, stream>>>(clas_preds, bbox_preds, bbox_tgts,
                                          clas_tgts, anchors,
                                          bb_part, fl_part, m_part);
    rnfl_final<<<1, 256, 0, stream>>>(bb_part, fl_part, m_part, out);
}